// Round 10
// baseline (71.887 us; speedup 1.0000x reference)
//
#include <hip/hip_runtime.h>
#include <math.h>

#define TT 1024
#define NN 64
#define CC 128
#define SS 128
#define NCH 64         // chunks of 16 time steps (8 two-step blocks)
#define NC (NN * CC)   // floats between time rows

typedef float f4 __attribute__((ext_vector_type(4)));

// DPP controls (gfx9/CDNA encodings)
#define DPP_QP_XOR1   0xB1
#define DPP_QP_XOR2   0x4E
#define DPP_WAVE_SHR1 0x138
#define DPP_ROW_MIRR  0x140
#define DPP_HALF_MIRR 0x141
#define DPP_BCAST15   0x142
#define DPP_BCAST31   0x143

template <int CTRL>
__device__ __forceinline__ float dpp_max_stage(float v) {
    int p = __builtin_amdgcn_update_dpp(__float_as_int(v), __float_as_int(v),
                                        CTRL, 0xF, 0xF, false);
    return fmaxf(v, __int_as_float(p));
}
__device__ __forceinline__ float dpp_shr1(float v) {   // prev lane, lane0 -> 0
    int p = __builtin_amdgcn_update_dpp(0, __float_as_int(v),
                                        DPP_WAVE_SHR1, 0xF, 0xF, true);
    return __int_as_float(p);
}

#define DSR(dst, addr, off) \
    asm volatile("ds_read_b128 %0, %1 offset:" #off : "=v"(dst) : "v"(addr))
#define LGKM(n) do { \
    asm volatile("s_waitcnt lgkmcnt(" #n ")" ::: "memory"); \
    __builtin_amdgcn_sched_barrier(0); } while (0)
#define VMC(n) do { \
    asm volatile("s_waitcnt vmcnt(" #n ")" ::: "memory"); \
    __builtin_amdgcn_sched_barrier(0); } while (0)
#define BARRIER() asm volatile("s_barrier" ::: "memory")
#define ISSUE_C(g, bb) do { const unsigned ab = base_C + (bb) * 5120u; \
    DSR(g##0, ab, 0); DSR(g##1, ab, 1024); DSR(g##2, ab, 2048); \
    DSR(g##3, ab, 3072); DSR(g##4, ab, 4096); } while (0)

// CTC forward with 2-step time blocking. One block per batch element n.
// Wave 0 = consumer: 8 two-step blocks per chunk, alpha in registers,
//   asm ds_read_b128 coef pipeline (verified round-8 LGKM pattern).
// Waves 1-4 = producers: stage rows coalesced (global_load_lds), build the
//   banded 2-step operator coefficients + plain per-step emissions in LDS.
// Chunk 0 and the capture chunk run the verified 1-step path (odd-t capture).
__global__ __launch_bounds__(320, 1) void ctc_scan(
    const float* __restrict__ lp,        // [T, N, C] fp32 log-softmax
    const int*   __restrict__ targets,   // [N, S]
    const int*   __restrict__ ilen,      // [N]
    const int*   __restrict__ tlen,      // [N]
    float*       __restrict__ v_out)     // [N] terminal log-alpha
{
    const int n    = blockIdx.x;
    const int tid  = threadIdx.x;
    const int wv   = tid >> 6;           // 0 = consumer, 1..4 = producers
    const int lane = tid & 63;

    __shared__ float  s_rows[2][16][CC];   // 16 KiB staged lp rows
    __shared__ f4     s_C[2][8][5][64];    // 80 KiB 2-step coefs [buf][blk][quad][lane]
    __shared__ float4 s_e[2][8][64];       // 16 KiB plain emissions (x1,x3,y1,y3)
    __shared__ float  s_pb[2][8][2];       // blank probs per (blk, step-in-blk)

    const int tgA  = targets[n * SS + 2 * lane];
    const int tgB  = targets[n * SS + 2 * lane + 1];
    const int tgBm = (lane > 0) ? targets[n * SS + 2 * lane - 1] : -1;
    const float k1f = (lane > 0 && tgA != tgBm) ? 1.f : 0.f;
    const float k3f = (tgB != tgA) ? 1.f : 0.f;
    const float* lpn = lp + (size_t)n * CC;      // row t at lpn + t*NC

    const int w = wv - 1;                // producer index 0..3 (wv!=0)
    const float km1f = dpp_shr1(k3f);    // prev lane's k3 flag (const)

    // stage 4 rows (2 instrs x 2 rows) of chunk c into s_rows[buf]
    auto stage_rows = [&](int c, int buf) {
#pragma unroll
        for (int i = 0; i < 2; ++i) {
            const int r = 4 * w + 2 * i;
            int t = 1 + 16 * c + r + (lane >> 5);
            if (t > TT - 1) t = TT - 1;
            const float* src = lpn + (size_t)t * NC + (lane & 31) * 4;
            __builtin_amdgcn_global_load_lds(
                (const __attribute__((address_space(1))) void*)src,
                (__attribute__((address_space(3))) void*)&s_rows[buf][r][0],
                16, 0, 0);
        }
    };

    // build 2-step operator coefs + plain emissions for this wave's 2 blocks.
    // Derivation (verified by hand vs 1-step composition, states 0..3 + general):
    //  T: a'[s] = e[s](a[s]+a[s-1]+k_s a[s-2]);  C = T2.T1 band-4.
    //  even s skip flag = 0 (both blanks);  C[4l,4l-4] = 0  -> a0p never needed.
    //  Boost 2^12 folded into e2 (b2,y1,y3) keeps 16-step renorm window out of
    //  denormals; consumer subtracts 96*ln2 per chunk from ls.
    auto build = [&](int buf) {
#pragma unroll
        for (int i = 0; i < 2; ++i) {
            const int blk = 2 * w + i;
            const int r1 = 2 * blk, r2 = r1 + 1;
            const float b1  = __expf(s_rows[buf][r1][0]);
            const float x1  = __expf(s_rows[buf][r1][tgA]);
            const float x3  = __expf(s_rows[buf][r1][tgB]);
            const float b2r = __expf(s_rows[buf][r2][0]);
            const float y1r = __expf(s_rows[buf][r2][tgA]);
            const float y3r = __expf(s_rows[buf][r2][tgB]);
            s_e[buf][blk][lane] = make_float4(x1, x3, y1r, y3r);
            if (lane == 0) { s_pb[buf][blk][0] = b1; s_pb[buf][blk][1] = b2r; }

            const float B = 4096.f;                       // 2^12 boost
            const float b2 = b2r * B, y1 = y1r * B, y3 = y3r * B;
            const float xm1 = dpp_shr1(x3);               // e1[4p-1]

            const float C00 = b2 * b1;
            const float C02 = b2 * xm1;
            const float C01 = C00 + C02;
            const float C03 = km1f * C02;
            const float C10 = y1 * x1;
            const float C11 = y1 * (x1 + b1);
            const float C12 = y1 * fmaf(k1f, x1 + xm1, b1);
            const float C13 = y1 * (k1f * xm1);
            const float C14 = km1f * C13;
            const float C20 = C00;
            const float C22 = b2 * x1;
            const float C21 = C20 + C22;
            const float C23 = k1f * C22;
            const float C30 = y3 * x3;
            const float C31 = y3 * (x3 + b1);
            const float C32 = y3 * fmaf(k3f, x3 + x1, b1);
            const float C33 = y3 * (k3f * x1);
            const float C34 = k1f * C33;

            s_C[buf][blk][0][lane] = (f4){C00, C01, C02, C03};
            s_C[buf][blk][1][lane] = (f4){C10, C11, C12, C13};
            s_C[buf][blk][2][lane] = (f4){C14, C20, C21, C22};
            s_C[buf][blk][3][lane] = (f4){C23, C30, C31, C32};
            s_C[buf][blk][4][lane] = (f4){C33, C34, 0.f, 0.f};
        }
    };

    const int il    = ilen[n];
    const int vs    = 2 * tlen[n] - 1;   // odd, in [127, 255]
    const int vlane = vs >> 2;
    const int capc  = (il - 2) >> 4;     // chunk containing t = il-1 (in [31,63])

    float a0 = 1.f, a1 = 1.f, a2 = 1.f, a3 = 1.f, ls = 0.f;
    if (wv == 0) {
        a0 = (lane == 0) ? __expf(lpn[0])   : 1.f;
        a1 = (lane == 0) ? __expf(lpn[tgA]) : 1.f;
    }
    float mr = 1.f, inv = 1.f;

    const unsigned base_C0 = (unsigned)(size_t)(void*)&s_C[0][0][0][lane];

    if (wv != 0) {
        stage_rows(0, 0); stage_rows(1, 1);
        VMC(2);                    // chunk-0 rows done (chunk-1 in flight)
        build(0);
        asm volatile("s_waitcnt lgkmcnt(0)" ::: "memory");
    }
    BARRIER();

    for (int cc = 0; cc < NCH; ++cc) {
        const int b = cc & 1;
        if (wv == 0) {
            if (cc == 0 || cc == capc) {
                // ---- verified 1-step path (16 steps) ----
                const int t0c = 1 + 16 * cc;
                float a3p = dpp_shr1(a3);
#pragma unroll
                for (int j = 0; j < 16; ++j) {
                    const int k = j >> 1;
                    const float4 e  = s_e[b][k][lane];
                    const float cpb = s_pb[b][k][j & 1];
                    const float cpa = (j & 1) ? e.z : e.x;
                    const float cpc = (j & 1) ? e.w : e.y;

                    float nb3 = fmaf(k3f, a1, a3 + a2) * cpc;
                    float a3pn = dpp_shr1(nb3);
                    float nb0 = (a0 + a3p) * cpb;
                    float nb1 = fmaf(k1f, a3p, a0 + a1) * cpa;
                    float nb2 = (a2 + a1) * cpb;

                    const int jj = j & 7;
                    if      (jj == 0) mr = fmaxf(fmaxf(nb0, nb1), fmaxf(nb2, nb3));
                    else if (jj == 1) mr = dpp_max_stage<DPP_QP_XOR1>(mr);
                    else if (jj == 2) mr = dpp_max_stage<DPP_QP_XOR2>(mr);
                    else if (jj == 3) mr = dpp_max_stage<DPP_HALF_MIRR>(mr);
                    else if (jj == 4) mr = dpp_max_stage<DPP_ROW_MIRR>(mr);
                    else if (jj == 5) mr = dpp_max_stage<DPP_BCAST15>(mr);
                    else if (jj == 6) mr = dpp_max_stage<DPP_BCAST31>(mr);
                    else {
                        const float mru = __int_as_float(
                            __builtin_amdgcn_readlane(__float_as_int(mr), 63));
                        inv = 1.0f / mru;
                        ls += __logf(mru);
                        nb0 *= inv; nb1 *= inv; nb2 *= inv; nb3 *= inv;
                    }

                    const int t = t0c + j;
                    if (t == il - 1 && lane == vlane)
                        v_out[n] = __logf((vs & 2) ? nb3 : nb1) + ls;

                    a0 = nb0; a1 = nb1; a2 = nb2; a3 = nb3;
                    if (jj == 7) a3pn *= inv;
                    a3p = a3pn;
                }
            } else {
                // ---- blocked path: 8 two-step blocks ----
                const unsigned base_C = base_C0 + (unsigned)(b * 40960);
                f4 gqA0, gqA1, gqA2, gqA3, gqA4;
                f4 gqB0, gqB1, gqB2, gqB3, gqB4;
                f4 gqC0, gqC1, gqC2, gqC3, gqC4;

                auto bstep = [&](const f4 q0, const f4 q1, const f4 q2,
                                 const f4 q3, const f4 q4, const int bb) {
                    const float a1p = dpp_shr1(a1);
                    const float a2p = dpp_shr1(a2);
                    const float a3p = dpp_shr1(a3);
                    float n0 = q0[0] * a0;
                    n0 = fmaf(q0[1], a3p, n0); n0 = fmaf(q0[2], a2p, n0);
                    n0 = fmaf(q0[3], a1p, n0);
                    float n1 = q1[0] * a1;
                    n1 = fmaf(q1[1], a0, n1);  n1 = fmaf(q1[2], a3p, n1);
                    n1 = fmaf(q1[3], a2p, n1); n1 = fmaf(q2[0], a1p, n1);
                    float n2 = q2[1] * a2;
                    n2 = fmaf(q2[2], a1, n2);  n2 = fmaf(q2[3], a0, n2);
                    n2 = fmaf(q3[0], a3p, n2);
                    float n3 = q3[1] * a3;
                    n3 = fmaf(q3[2], a2, n3);  n3 = fmaf(q3[3], a1, n3);
                    n3 = fmaf(q4[0], a0, n3);  n3 = fmaf(q4[1], a3p, n3);

                    if      (bb == 0) mr = fmaxf(fmaxf(n0, n1), fmaxf(n2, n3));
                    else if (bb == 1) mr = dpp_max_stage<DPP_QP_XOR1>(mr);
                    else if (bb == 2) mr = dpp_max_stage<DPP_QP_XOR2>(mr);
                    else if (bb == 3) mr = dpp_max_stage<DPP_HALF_MIRR>(mr);
                    else if (bb == 4) mr = dpp_max_stage<DPP_ROW_MIRR>(mr);
                    else if (bb == 5) mr = dpp_max_stage<DPP_BCAST15>(mr);
                    else if (bb == 6) mr = dpp_max_stage<DPP_BCAST31>(mr);
                    else {
                        const float mru = __int_as_float(
                            __builtin_amdgcn_readlane(__float_as_int(mr), 63));
                        inv = 1.0f / mru;
                        ls += __logf(mru) - 66.542129f;   // -96*ln2 boost comp
                        n0 *= inv; n1 *= inv; n2 *= inv; n3 *= inv;
                    }
                    a0 = n0; a1 = n1; a2 = n2; a3 = n3;
                };

                ISSUE_C(gqA, 0); ISSUE_C(gqB, 1);
                ISSUE_C(gqC, 2); LGKM(10); bstep(gqA0, gqA1, gqA2, gqA3, gqA4, 0);
                ISSUE_C(gqA, 3); LGKM(10); bstep(gqB0, gqB1, gqB2, gqB3, gqB4, 1);
                ISSUE_C(gqB, 4); LGKM(10); bstep(gqC0, gqC1, gqC2, gqC3, gqC4, 2);
                ISSUE_C(gqC, 5); LGKM(10); bstep(gqA0, gqA1, gqA2, gqA3, gqA4, 3);
                ISSUE_C(gqA, 6); LGKM(10); bstep(gqB0, gqB1, gqB2, gqB3, gqB4, 4);
                ISSUE_C(gqB, 7); LGKM(10); bstep(gqC0, gqC1, gqC2, gqC3, gqC4, 5);
                                 LGKM(5);  bstep(gqA0, gqA1, gqA2, gqA3, gqA4, 6);
                                 LGKM(0);  bstep(gqB0, gqB1, gqB2, gqB3, gqB4, 7);
            }
        } else {
            stage_rows(cc + 2, b);        // buf (cc+2)&1 == b; clamped past end
            VMC(2);                       // chunk cc+1 rows complete
            if (cc + 1 < NCH) build((cc + 1) & 1);
            asm volatile("s_waitcnt lgkmcnt(0)" ::: "memory");
        }
        BARRIER();
    }
}

// loss = -logsumexp(v) over the 64 batch elements; single wave
__global__ void ctc_reduce(const float* __restrict__ v, float* __restrict__ out)
{
    const int lane = threadIdx.x;
    float x = v[lane];
    float m = x;
#pragma unroll
    for (int off = 32; off > 0; off >>= 1) m = fmaxf(m, __shfl_xor(m, off));
    float e = __expf(x - m);
#pragma unroll
    for (int off = 32; off > 0; off >>= 1) e += __shfl_xor(e, off);
    if (lane == 0) out[0] = -(m + __logf(e));
}

extern "C" void kernel_launch(void* const* d_in, const int* in_sizes, int n_in,
                              void* d_out, int out_size, void* d_ws, size_t ws_size,
                              hipStream_t stream) {
    const float* lp      = (const float*)d_in[0];
    const int*   targets = (const int*)d_in[1];
    const int*   ilen    = (const int*)d_in[2];
    const int*   tlen    = (const int*)d_in[3];

    float* v   = (float*)d_ws;    // 64 floats of scratch
    float* out = (float*)d_out;

    ctc_scan<<<NN, 320, 0, stream>>>(lp, targets, ilen, tlen, v);
    ctc_reduce<<<1, 64, 0, stream>>>(v, out);
}